// Round 15
// baseline (45.316 us; speedup 1.0000x reference)
//
#include <hip/hip_runtime.h>

// RDF loss: all-pairs distance histogram (10 unit bins) -> rdf -> MSE.
// Two kernels (r9 lesson: device-fence ticket serializes the chip).
// r15: raise latency-covering parallelism ILPxTLP 2x -- IBLK=8 independent
// pair-chains per lane AND JCH=32 (finer j-chunks): 1344 blocks x 4 waves
// = 5376 waves (~21/CU) x 8 chains = ~42 chains/SIMD (r11-r14 all had ~20;
// the idle was constant across them because the product never changed).
// Per-block pair work unchanged (2048x32 == 1024x64). One broadcast
// ds_read_b128 per j feeds 8 pairs. Window = 4 j x 8 pairs = 32 adds into
// a single u64 packed counter (10 fields x 6 bits, <=32 < 63 per field;
// trash field at bits 60+ overflows off the register top harmlessly).
// Pair math (verified absmax==0): Gram-form d2 (coords pre-scaled 1/dr) ->
// v_pk_fma_f32 -> v_sqrt -> v_cvt_u32 (sat, NaN->0) -> min(b,10) -> 1ull<<6b.
// Reference emulation: fp32 segment_sum saturates at 2^24 -> clamp per bin.

#define BLOCK    256
#define IBLK     8
#define ITILE    (BLOCK * IBLK)   // 2048
#define JCH      32
#define DJC      (ITILE / JCH)    // 64 j-chunks per i-tile
#define NB       10
#define SLOT     16               // u32 stride between block-partial rows
#define FP32_SAT 16777216u        // 2^24

typedef float f32x2 __attribute__((ext_vector_type(2)));

__device__ __forceinline__ int pre_rows(int k, int njc) {
    // blocks before i-tile k: sum_{m<k} (njc - DJC*m)
    return k * njc - (DJC / 2) * k * (k - 1);
}

template <bool STRADDLE>
__device__ __forceinline__ void jloop(const float4* __restrict__ sj,
                                      const f32x2* sqiv, const f32x2* m2xv,
                                      const f32x2* m2yv, const f32x2* m2zv,
                                      const int* iidx, int jbase,
                                      unsigned int* c)
{
    #pragma unroll 1
    for (int jc0 = 0; jc0 < JCH; jc0 += 4) {
        unsigned long long cnt = 0ull;
        #pragma unroll
        for (int jj = 0; jj < 4; ++jj) {
            const int j = jc0 + jj;
            float4 p = sj[j];
            const f32x2 pw = {p.w, p.w}, px = {p.x, p.x};
            const f32x2 py = {p.y, p.y}, pz = {p.z, p.z};
            #pragma unroll
            for (int rp = 0; rp < IBLK / 2; ++rp) {       // 4 f32x2 chains
                f32x2 d2 = sqiv[rp] + pw;
                d2 = __builtin_elementwise_fma(m2xv[rp], px, d2);  // v_pk_fma_f32
                d2 = __builtin_elementwise_fma(m2yv[rp], py, d2);
                d2 = __builtin_elementwise_fma(m2zv[rp], pz, d2);
                float d2a = d2.x, d2b = d2.y;
                if (STRADDLE) {
                    d2a = (jbase + j > iidx[2 * rp])     ? d2a : 3.0e30f;
                    d2b = (jbase + j > iidx[2 * rp + 1]) ? d2b : 3.0e30f;
                }
                float da = __builtin_amdgcn_sqrtf(d2a);
                float db = __builtin_amdgcn_sqrtf(d2b);
                unsigned int ba = min((unsigned int)da, 10u);  // cvt sat, NaN->0
                unsigned int bb = min((unsigned int)db, 10u);  // 10 = trash field
                cnt += 1ull << (ba * 6u);
                cnt += 1ull << (bb * 6u);
            }
        }
        #pragma unroll
        for (int k = 0; k < NB; ++k)
            c[k] += (unsigned int)(cnt >> (6 * k)) & 63u;
    }
}

__global__ __launch_bounds__(BLOCK) void rdf_hist_kernel(
    const float* __restrict__ pc, const int* __restrict__ rmaxp,
    const float* __restrict__ drp, unsigned int* __restrict__ part,
    int n, int nI, int njc)
{
    __shared__ float4 sj[JCH];
    __shared__ unsigned int sacc[NB];

    const int tid = threadIdx.x;
    const int bid = (int)blockIdx.x;

    // decode dense triangular work index -> (i-tile k, j-chunk jc)
    const float a  = (float)(DJC / 2);                 // 32
    const float bq = (float)njc + a;
    float disc = fmaxf(bq * bq - 4.0f * a * (float)bid, 0.0f);
    int k = (int)((bq - sqrtf(disc)) / (2.0f * a));
    k = max(0, min(k, nI - 1));
    while (k > 0 && pre_rows(k, njc) > bid) --k;
    while (k + 1 < nI && pre_rows(k + 1, njc) <= bid) ++k;
    const int jc    = (bid - pre_rows(k, njc)) + DJC * k;
    const int ibase = k * ITILE;
    const int jbase = jc * JCH;

    const float inv_dr = 1.0f / (*drp);

    // issue all raw global loads before first use (single latency drain)
    float jx = -3.0e4f, jy = -3.0e4f, jz = -3.0e4f;    // j-pad sentinel
    if (tid < JCH) {
        const int j = jbase + tid;
        if (j < n) { jx = pc[3*j]; jy = pc[3*j+1]; jz = pc[3*j+2]; }
    }
    float rx[IBLK], ry[IBLK], rz[IBLK];
    int iidx[IBLK];
    #pragma unroll
    for (int r = 0; r < IBLK; ++r) {
        const int i = ibase + tid + BLOCK * r;
        iidx[r] = i;
        rx[r] = 3.0e4f; ry[r] = 3.0e4f; rz[r] = 3.0e4f; // i-pad: opposite sign
        if (i < n) { rx[r] = pc[3*i]; ry[r] = pc[3*i+1]; rz[r] = pc[3*i+2]; }
    }

    if (tid < NB) sacc[tid] = 0u;
    if (tid < JCH) {
        const float x = jx * inv_dr, y = jy * inv_dr, z = jz * inv_dr;
        sj[tid] = make_float4(x, y, z, x*x + y*y + z*z);
    }
    f32x2 sqiv[IBLK/2], m2xv[IBLK/2], m2yv[IBLK/2], m2zv[IBLK/2];
    #pragma unroll
    for (int r = 0; r < IBLK; ++r) {
        const float x = rx[r] * inv_dr, y = ry[r] * inv_dr, z = rz[r] * inv_dr;
        const float sq = x*x + y*y + z*z;
        sqiv[r/2][r&1] = sq;
        m2xv[r/2][r&1] = -2.f * x;
        m2yv[r/2][r&1] = -2.f * y;
        m2zv[r/2][r&1] = -2.f * z;
    }

    __syncthreads();

    unsigned int c[NB];
    #pragma unroll
    for (int q = 0; q < NB; ++q) c[q] = 0u;

    if (jbase < ibase + ITILE)                  // chunk straddles diagonal band
        jloop<true >(sj, sqiv, m2xv, m2yv, m2zv, iidx, jbase, c);
    else
        jloop<false>(sj, sqiv, m2xv, m2yv, m2zv, iidx, jbase, c);

    // wave butterfly -> LDS combine -> one non-atomic partial row per block
    #pragma unroll
    for (int q = 0; q < NB; ++q) {
        unsigned int s = c[q];
        #pragma unroll
        for (int m = 32; m >= 1; m >>= 1) s += (unsigned int)__shfl_xor((int)s, m, 64);
        c[q] = s;
    }
    if ((tid & 63) == 0) {
        #pragma unroll
        for (int q = 0; q < NB; ++q) atomicAdd(&sacc[q], c[q]);
    }
    __syncthreads();
    if (tid < NB) part[bid * SLOT + tid] = sacc[tid];
}

__global__ __launch_bounds__(256) void rdf_reduce_loss_kernel(
    const unsigned int* __restrict__ part, const float* __restrict__ target,
    const int* __restrict__ rmaxp, const float* __restrict__ drp,
    float* __restrict__ out, int n, int mt, int nblocks)
{
    __shared__ unsigned int sacc[NB];
    const int tid = threadIdx.x;
    if (tid < NB) sacc[tid] = 0u;
    __syncthreads();

    unsigned int a[NB];
    #pragma unroll
    for (int q = 0; q < NB; ++q) a[q] = 0u;
    for (int s = tid; s < nblocks; s += 256) {
        #pragma unroll
        for (int q = 0; q < NB; ++q) a[q] += part[s * SLOT + q];
    }
    #pragma unroll
    for (int q = 0; q < NB; ++q) {
        unsigned int s = a[q];
        #pragma unroll
        for (int m = 32; m >= 1; m >>= 1) s += (unsigned int)__shfl_xor((int)s, m, 64);
        if ((tid & 63) == 0) atomicAdd(&sacc[q], s);
    }
    __syncthreads();

    if (tid == 0) {
        const float PI = 3.14159265358979323846f;
        const float rmax = (float)(*rmaxp);
        const float dr   = *drp;
        int nbins = (int)roundf(rmax / dr);
        if (nbins > NB) nbins = NB;
        const float density = (float)n / (4.0f / 3.0f * PI * rmax * rmax * rmax);
        const int m = (mt < nbins) ? mt : nbins;
        float acc = 0.0f;
        for (int b = 0; b < m; ++b) {
            unsigned int hb = 2u * sacc[b] + ((b == 0) ? (unsigned int)n : 0u);
            if (hb > FP32_SAT) hb = FP32_SAT;   // fp32 segment_sum saturation
            float r_mid = ((float)b + 0.5f) * dr;
            float ideal = 4.0f * PI * r_mid * r_mid * dr * density * (float)n;
            float rdf  = (ideal != 0.0f) ? ((float)hb / ideal) : 0.0f;
            float diff = rdf - target[b];
            acc = fmaf(diff, diff, acc);
        }
        out[0] = acc / (float)m;
    }
}

extern "C" void kernel_launch(void* const* d_in, const int* in_sizes, int n_in,
                              void* d_out, int out_size, void* d_ws, size_t ws_size,
                              hipStream_t stream)
{
    const float* pc     = (const float*)d_in[0];
    const float* target = (const float*)d_in[1];
    const int*   rmaxp  = (const int*)d_in[2];
    const float* drp    = (const float*)d_in[3];
    const int n  = in_sizes[0] / 3;
    const int mt = in_sizes[1];

    unsigned int* part = (unsigned int*)d_ws;
    const int nI  = (n + ITILE - 1) / ITILE;
    const int njc = (n + JCH - 1) / JCH;
    const int nblocks = nI * njc - (DJC / 2) * nI * (nI - 1); // dense triangle

    rdf_hist_kernel<<<nblocks, BLOCK, 0, stream>>>(pc, rmaxp, drp, part, n, nI, njc);
    rdf_reduce_loss_kernel<<<1, 256, 0, stream>>>(part, target, rmaxp, drp,
                                                  (float*)d_out, n, mt, nblocks);
}

// Round 16
// 39.606 us; speedup vs baseline: 1.1442x; 1.1442x over previous
//
#include <hip/hip_runtime.h>

// RDF loss: all-pairs distance histogram (10 unit bins) -> rdf -> MSE.
// FINAL-BEST configuration (= round 11, 39.7 us; rounds 12-15 tested
// counter-split, code-size, block-size, and ILPxTLP variants -- all null
// or regressions; restored exactly).
// Two kernels (r9 lesson: device-fence ticket serializes the chip).
// Dense triangular grid of (i-tile=1024, j-chunk=64) blocks: 1248 uniform
// blocks. IBLK=4 i-points/lane as two f32x2 v_pk_fma_f32 chains; one
// broadcast ds_read_b128 per j feeds 4 pairs. Single u64 packed counter
// per 8-j window (10 fields x 6 bits, 32 adds max < 63; field 10 = trash
// for d>rmax / pads / masked diagonal, overflow falls off the register).
// Pair math (verified absmax==0): Gram-form d2 (coords pre-scaled 1/dr) ->
// v_sqrt -> v_cvt_u32 (sat, NaN->0) -> min(b,10) -> 1ull<<(6b).
// Reference emulation: fp32 segment_sum saturates at 2^24 -> clamp per bin.

#define BLOCK    256
#define IBLK     4
#define ITILE    (BLOCK * IBLK)   // 1024
#define JCH      64
#define DJC      (ITILE / JCH)    // 16 j-chunks per i-tile
#define NB       10
#define SLOT     16               // u32 stride between block-partial rows
#define FP32_SAT 16777216u        // 2^24

typedef float f32x2 __attribute__((ext_vector_type(2)));

__device__ __forceinline__ int pre_rows(int k, int njc) {
    // blocks before i-tile k: sum_{m<k} (njc - DJC*m)
    return k * njc - (DJC / 2) * k * (k - 1);
}

template <bool STRADDLE>
__device__ __forceinline__ void jloop(const float4* __restrict__ sj,
                                      const f32x2* sqiv, const f32x2* m2xv,
                                      const f32x2* m2yv, const f32x2* m2zv,
                                      const int* iidx, int jbase,
                                      unsigned int* c)
{
    #pragma unroll
    for (int jc0 = 0; jc0 < JCH; jc0 += 8) {
        unsigned long long cnt = 0ull;
        #pragma unroll
        for (int jj = 0; jj < 8; ++jj) {
            const int j = jc0 + jj;
            float4 p = sj[j];
            const f32x2 pw = {p.w, p.w}, px = {p.x, p.x};
            const f32x2 py = {p.y, p.y}, pz = {p.z, p.z};
            #pragma unroll
            for (int rp = 0; rp < IBLK / 2; ++rp) {
                f32x2 d2 = sqiv[rp] + pw;
                d2 = __builtin_elementwise_fma(m2xv[rp], px, d2);  // v_pk_fma_f32
                d2 = __builtin_elementwise_fma(m2yv[rp], py, d2);
                d2 = __builtin_elementwise_fma(m2zv[rp], pz, d2);
                float d2a = d2.x, d2b = d2.y;
                if (STRADDLE) {
                    d2a = (jbase + j > iidx[2 * rp])     ? d2a : 3.0e30f;
                    d2b = (jbase + j > iidx[2 * rp + 1]) ? d2b : 3.0e30f;
                }
                float da = __builtin_amdgcn_sqrtf(d2a);
                float db = __builtin_amdgcn_sqrtf(d2b);
                unsigned int ba = min((unsigned int)da, 10u);  // cvt sat, NaN->0
                unsigned int bb = min((unsigned int)db, 10u);  // 10 = trash field
                cnt += 1ull << (ba * 6u);
                cnt += 1ull << (bb * 6u);
            }
        }
        #pragma unroll
        for (int k = 0; k < NB; ++k)
            c[k] += (unsigned int)(cnt >> (6 * k)) & 63u;
    }
}

__global__ __launch_bounds__(BLOCK) void rdf_hist_kernel(
    const float* __restrict__ pc, const int* __restrict__ rmaxp,
    const float* __restrict__ drp, unsigned int* __restrict__ part,
    int n, int nI, int njc)
{
    __shared__ float4 sj[JCH];
    __shared__ unsigned int sacc[NB];

    const int tid = threadIdx.x;
    const int bid = (int)blockIdx.x;

    // decode dense triangular work index -> (i-tile k, j-chunk jc)
    const float a  = (float)(DJC / 2);                 // 8
    const float bq = (float)njc + a;
    float disc = fmaxf(bq * bq - 4.0f * a * (float)bid, 0.0f);
    int k = (int)((bq - sqrtf(disc)) / (2.0f * a));
    k = max(0, min(k, nI - 1));
    while (k > 0 && pre_rows(k, njc) > bid) --k;
    while (k + 1 < nI && pre_rows(k + 1, njc) <= bid) ++k;
    const int jc    = (bid - pre_rows(k, njc)) + DJC * k;
    const int ibase = k * ITILE;
    const int jbase = jc * JCH;

    const float inv_dr = 1.0f / (*drp);

    // issue all raw global loads before first use (single latency drain)
    float jx = -3.0e4f, jy = -3.0e4f, jz = -3.0e4f;    // j-pad sentinel
    if (tid < JCH) {
        const int j = jbase + tid;
        if (j < n) { jx = pc[3*j]; jy = pc[3*j+1]; jz = pc[3*j+2]; }
    }
    float rx[IBLK], ry[IBLK], rz[IBLK];
    int iidx[IBLK];
    #pragma unroll
    for (int r = 0; r < IBLK; ++r) {
        const int i = ibase + tid + BLOCK * r;
        iidx[r] = i;
        rx[r] = 3.0e4f; ry[r] = 3.0e4f; rz[r] = 3.0e4f; // i-pad: opposite sign
        if (i < n) { rx[r] = pc[3*i]; ry[r] = pc[3*i+1]; rz[r] = pc[3*i+2]; }
    }

    if (tid < NB) sacc[tid] = 0u;
    if (tid < JCH) {
        const float x = jx * inv_dr, y = jy * inv_dr, z = jz * inv_dr;
        sj[tid] = make_float4(x, y, z, x*x + y*y + z*z);
    }
    f32x2 sqiv[IBLK/2], m2xv[IBLK/2], m2yv[IBLK/2], m2zv[IBLK/2];
    #pragma unroll
    for (int r = 0; r < IBLK; ++r) {
        const float x = rx[r] * inv_dr, y = ry[r] * inv_dr, z = rz[r] * inv_dr;
        const float sq = x*x + y*y + z*z;
        sqiv[r/2][r&1] = sq;
        m2xv[r/2][r&1] = -2.f * x;
        m2yv[r/2][r&1] = -2.f * y;
        m2zv[r/2][r&1] = -2.f * z;
    }

    __syncthreads();

    unsigned int c[NB];
    #pragma unroll
    for (int q = 0; q < NB; ++q) c[q] = 0u;

    if (jbase < ibase + ITILE)                  // chunk straddles diagonal band
        jloop<true >(sj, sqiv, m2xv, m2yv, m2zv, iidx, jbase, c);
    else
        jloop<false>(sj, sqiv, m2xv, m2yv, m2zv, iidx, jbase, c);

    // wave butterfly -> LDS combine -> one non-atomic partial row per block
    #pragma unroll
    for (int q = 0; q < NB; ++q) {
        unsigned int s = c[q];
        #pragma unroll
        for (int m = 32; m >= 1; m >>= 1) s += (unsigned int)__shfl_xor((int)s, m, 64);
        c[q] = s;
    }
    if ((tid & 63) == 0) {
        #pragma unroll
        for (int q = 0; q < NB; ++q) atomicAdd(&sacc[q], c[q]);
    }
    __syncthreads();
    if (tid < NB) part[bid * SLOT + tid] = sacc[tid];
}

__global__ __launch_bounds__(BLOCK) void rdf_reduce_loss_kernel(
    const unsigned int* __restrict__ part, const float* __restrict__ target,
    const int* __restrict__ rmaxp, const float* __restrict__ drp,
    float* __restrict__ out, int n, int mt, int nblocks)
{
    __shared__ unsigned int sacc[NB];
    const int tid = threadIdx.x;
    if (tid < NB) sacc[tid] = 0u;
    __syncthreads();

    unsigned int a[NB];
    #pragma unroll
    for (int q = 0; q < NB; ++q) a[q] = 0u;
    for (int s = tid; s < nblocks; s += BLOCK) {
        #pragma unroll
        for (int q = 0; q < NB; ++q) a[q] += part[s * SLOT + q];
    }
    #pragma unroll
    for (int q = 0; q < NB; ++q) {
        unsigned int s = a[q];
        #pragma unroll
        for (int m = 32; m >= 1; m >>= 1) s += (unsigned int)__shfl_xor((int)s, m, 64);
        if ((tid & 63) == 0) atomicAdd(&sacc[q], s);
    }
    __syncthreads();

    if (tid == 0) {
        const float PI = 3.14159265358979323846f;
        const float rmax = (float)(*rmaxp);
        const float dr   = *drp;
        int nbins = (int)roundf(rmax / dr);
        if (nbins > NB) nbins = NB;
        const float density = (float)n / (4.0f / 3.0f * PI * rmax * rmax * rmax);
        const int m = (mt < nbins) ? mt : nbins;
        float acc = 0.0f;
        for (int b = 0; b < m; ++b) {
            unsigned int hb = 2u * sacc[b] + ((b == 0) ? (unsigned int)n : 0u);
            if (hb > FP32_SAT) hb = FP32_SAT;   // fp32 segment_sum saturation
            float r_mid = ((float)b + 0.5f) * dr;
            float ideal = 4.0f * PI * r_mid * r_mid * dr * density * (float)n;
            float rdf  = (ideal != 0.0f) ? ((float)hb / ideal) : 0.0f;
            float diff = rdf - target[b];
            acc = fmaf(diff, diff, acc);
        }
        out[0] = acc / (float)m;
    }
}

extern "C" void kernel_launch(void* const* d_in, const int* in_sizes, int n_in,
                              void* d_out, int out_size, void* d_ws, size_t ws_size,
                              hipStream_t stream)
{
    const float* pc     = (const float*)d_in[0];
    const float* target = (const float*)d_in[1];
    const int*   rmaxp  = (const int*)d_in[2];
    const float* drp    = (const float*)d_in[3];
    const int n  = in_sizes[0] / 3;
    const int mt = in_sizes[1];

    unsigned int* part = (unsigned int*)d_ws;
    const int nI  = (n + ITILE - 1) / ITILE;
    const int njc = (n + JCH - 1) / JCH;
    const int nblocks = nI * njc - (DJC / 2) * nI * (nI - 1); // dense triangle

    rdf_hist_kernel<<<nblocks, BLOCK, 0, stream>>>(pc, rmaxp, drp, part, n, nI, njc);
    rdf_reduce_loss_kernel<<<1, BLOCK, 0, stream>>>(part, target, rmaxp, drp,
                                                    (float*)d_out, n, mt, nblocks);
}